// Round 1
// baseline (680.003 us; speedup 1.0000x reference)
//
#include <hip/hip_runtime.h>
#include <math.h>

#define IN_DIM 128
#define OUT_DIM 64
#define NEG_SLOPE 0.01f

// float atomic max via monotone int/uint trick (init must be -inf)
__device__ __forceinline__ void atomicMaxFloat(float* addr, float val) {
  if (val >= 0.f) {
    atomicMax((int*)addr, __float_as_int(val));
  } else {
    atomicMin((unsigned int*)addr, __float_as_uint(val));
  }
}

// ---------------- init: m=-inf, denom=0, count=0 ----------------
__global__ void init_kernel(float* __restrict__ m, float* __restrict__ denom,
                            int* __restrict__ count, int N) {
  int i = blockIdx.x * blockDim.x + threadIdx.x;
  if (i < N) { m[i] = -INFINITY; denom[i] = 0.f; count[i] = 0; }
}

// ---------------- fc: z = h @ W ; s = z@a_l ; t = z@a_r ----------------
// block = 256 threads (4 waves), 64 nodes per block, wave handles 16 nodes,
// lane = output column. h-tile + W in LDS (exactly 64 KiB).
__global__ __launch_bounds__(256) void fc_kernel(
    const float* __restrict__ h, const float* __restrict__ W,
    const float* __restrict__ al, const float* __restrict__ ar,
    float* __restrict__ z, float* __restrict__ s, float* __restrict__ t, int N) {
  __shared__ float hlds[64][IN_DIM];     // 32 KiB
  __shared__ float Wl[IN_DIM][OUT_DIM];  // 32 KiB
  int tid = threadIdx.x;
  int nb = blockIdx.x * 64;

  // stage W (linear, coalesced float4)
  for (int i = tid; i < IN_DIM * OUT_DIM / 4; i += 256)
    ((float4*)Wl)[i] = ((const float4*)W)[i];

  // stage h tile (coalesced float4 per row-quad)
  for (int it = tid; it < 64 * (IN_DIM / 4); it += 256) {
    int r = it >> 5;        // 0..63  (IN_DIM/4 == 32)
    int kq = it & 31;
    int row = nb + r;
    float4 v = make_float4(0.f, 0.f, 0.f, 0.f);
    if (row < N) v = *(const float4*)&h[(size_t)row * IN_DIM + kq * 4];
    *(float4*)&hlds[r][kq * 4] = v;
  }
  __syncthreads();

  int lane = tid & 63, wid = tid >> 6;
  int n0 = wid * 16;  // 16 nodes per wave
  float acc[16];
#pragma unroll
  for (int i = 0; i < 16; ++i) acc[i] = 0.f;

  for (int kq = 0; kq < IN_DIM / 4; ++kq) {
    int k = kq * 4;
    float w0 = Wl[k + 0][lane];
    float w1 = Wl[k + 1][lane];
    float w2 = Wl[k + 2][lane];
    float w3 = Wl[k + 3][lane];
#pragma unroll
    for (int nn = 0; nn < 16; ++nn) {
      float4 hv = *(const float4*)&hlds[n0 + nn][k];  // wave-uniform broadcast
      float a = acc[nn];
      a = fmaf(hv.x, w0, a);
      a = fmaf(hv.y, w1, a);
      a = fmaf(hv.z, w2, a);
      a = fmaf(hv.w, w3, a);
      acc[nn] = a;
    }
  }

  float alv = al[lane], arv = ar[lane];
#pragma unroll
  for (int nn = 0; nn < 16; ++nn) {
    int row = nb + n0 + nn;
    float p = acc[nn] * alv;
    float q = acc[nn] * arv;
#pragma unroll
    for (int off = 32; off; off >>= 1) {
      p += __shfl_down(p, off);
      q += __shfl_down(q, off);
    }
    if (row < N) {
      z[(size_t)row * OUT_DIM + lane] = acc[nn];
      if (lane == 0) { s[row] = p; t[row] = q; }
    }
  }
}

// ---------------- edge pass 1: per-dst max + degree count ----------------
__global__ void edge_pass1(const int* __restrict__ src, const int* __restrict__ dst,
                           const float* __restrict__ s, const float* __restrict__ t,
                           float* __restrict__ m, int* __restrict__ count, int E) {
  int i = blockIdx.x * blockDim.x + threadIdx.x;
  if (i >= E) return;
  int d = dst[i];
  float e = s[src[i]] + t[d];
  e = e > 0.f ? e : NEG_SLOPE * e;
  atomicMaxFloat(&m[d], e);
  atomicAdd(&count[d], 1);
}

// ---------------- CSR build: block sums -> serial scan -> write offsets ----------------
__global__ __launch_bounds__(256) void scan_block_sums(const int* __restrict__ count, int N,
                                                       int* __restrict__ bsums) {
  int b = blockIdx.x, tid = threadIdx.x;
  int base = b * 2048;
  int sum = 0;
  for (int i = tid; i < 2048; i += 256) {
    int idx = base + i;
    if (idx < N) sum += count[idx];
  }
#pragma unroll
  for (int off = 32; off; off >>= 1) sum += __shfl_down(sum, off);
  __shared__ int ws[4];
  int lane = tid & 63, wid = tid >> 6;
  if (lane == 0) ws[wid] = sum;
  __syncthreads();
  if (tid == 0) bsums[b] = ws[0] + ws[1] + ws[2] + ws[3];
}

__global__ void scan_bsums(const int* __restrict__ bsums, int nb, int* __restrict__ bofs,
                           int* __restrict__ offs, int N, int E) {
  if (blockIdx.x == 0 && threadIdx.x == 0) {
    int run = 0;
    for (int i = 0; i < nb; ++i) { bofs[i] = run; run += bsums[i]; }
    offs[N] = E;
  }
}

__global__ __launch_bounds__(256) void scan_write(const int* __restrict__ count, int N,
                                                  const int* __restrict__ bofs,
                                                  int* __restrict__ offs,
                                                  int* __restrict__ cursor) {
  int b = blockIdx.x, tid = threadIdx.x;
  int base = b * 2048 + tid * 8;
  int v[8];
  int tot = 0;
#pragma unroll
  for (int i = 0; i < 8; ++i) {
    int idx = base + i;
    int c = (idx < N) ? count[idx] : 0;
    v[i] = c;
    tot += c;
  }
  int lane = tid & 63, wid = tid >> 6;
  int x = tot;
#pragma unroll
  for (int off = 1; off < 64; off <<= 1) {
    int y = __shfl_up(x, off);
    if (lane >= off) x += y;
  }
  __shared__ int wtot[4];
  if (lane == 63) wtot[wid] = x;
  __syncthreads();
  int wbase = 0;
  for (int w2 = 0; w2 < wid; ++w2) wbase += wtot[w2];
  int run = bofs[b] + wbase + (x - tot);  // exclusive prefix for this thread
#pragma unroll
  for (int i = 0; i < 8; ++i) {
    int idx = base + i;
    if (idx < N) { offs[idx] = run; cursor[idx] = run; }
    run += v[i];
  }
}

// ---------------- edge pass 2: denom + CSR scatter ----------------
__global__ void edge_pass2(const int* __restrict__ src, const int* __restrict__ dst,
                           const float* __restrict__ s, const float* __restrict__ t,
                           const float* __restrict__ m, float* __restrict__ denom,
                           int* __restrict__ cursor, int* __restrict__ eidx, int E) {
  int i = blockIdx.x * blockDim.x + threadIdx.x;
  if (i >= E) return;
  int d = dst[i];
  float e = s[src[i]] + t[d];
  e = e > 0.f ? e : NEG_SLOPE * e;
  float ex = __expf(e - m[d]);
  atomicAdd(&denom[d], ex);
  int pos = atomicAdd(&cursor[d], 1);
  eidx[pos] = i;
}

// ---------------- aggregate: one wave per dst node, lane = column ----------------
__global__ __launch_bounds__(256) void aggregate_kernel(
    const int* __restrict__ offs, const int* __restrict__ eidx,
    const int* __restrict__ src, const float* __restrict__ s, const float* __restrict__ t,
    const float* __restrict__ m, const float* __restrict__ denom,
    const float* __restrict__ z, float* __restrict__ out, int N) {
  int wid = threadIdx.x >> 6, lane = threadIdx.x & 63;
  int n = blockIdx.x * 4 + wid;
  if (n >= N) return;
  int beg = offs[n], end = offs[n + 1];
  float acc = 0.f;
  if (beg < end) {
    float tn = t[n], mn = m[n];
    float inv = 1.0f / denom[n];
    for (int p = beg; p < end; ++p) {
      int i = eidx[p];
      int sn = src[i];
      float e = s[sn] + tn;
      e = e > 0.f ? e : NEG_SLOPE * e;
      float w = __expf(e - mn) * inv;
      acc += w * z[(size_t)sn * OUT_DIM + lane];  // coalesced 256B row
    }
  }
  out[(size_t)n * OUT_DIM + lane] = acc;
}

extern "C" void kernel_launch(void* const* d_in, const int* in_sizes, int n_in,
                              void* d_out, int out_size, void* d_ws, size_t ws_size,
                              hipStream_t stream) {
  const float* h = (const float*)d_in[0];
  const int* src = (const int*)d_in[1];
  const int* dst = (const int*)d_in[2];
  const float* W = (const float*)d_in[3];
  const float* al = (const float*)d_in[4];
  const float* ar = (const float*)d_in[5];
  float* out = (float*)d_out;
  int N = in_sizes[0] / IN_DIM;
  int E = in_sizes[1];

  // workspace layout (all written before read every call)
  float* z = (float*)d_ws;                 // N*64
  float* s = z + (size_t)N * OUT_DIM;      // N
  float* t = s + N;                        // N
  float* m = t + N;                        // N
  float* denom = m + N;                    // N
  int* count = (int*)(denom + N);          // N
  int* offs = count + N;                   // N+1
  int* cursor = offs + N + 1;              // N
  int* eidx = cursor + N;                  // E
  int* bsums = eidx + E;                   // <=256
  int* bofs = bsums + 256;                 // <=256

  const int NB = (N + 2047) / 2048;

  hipLaunchKernelGGL(init_kernel, dim3((N + 255) / 256), dim3(256), 0, stream, m, denom, count, N);
  hipLaunchKernelGGL(fc_kernel, dim3((N + 63) / 64), dim3(256), 0, stream, h, W, al, ar, z, s, t, N);
  hipLaunchKernelGGL(edge_pass1, dim3((E + 255) / 256), dim3(256), 0, stream, src, dst, s, t, m, count, E);
  hipLaunchKernelGGL(scan_block_sums, dim3(NB), dim3(256), 0, stream, count, N, bsums);
  hipLaunchKernelGGL(scan_bsums, dim3(1), dim3(64), 0, stream, bsums, NB, bofs, offs, N, E);
  hipLaunchKernelGGL(scan_write, dim3(NB), dim3(256), 0, stream, count, N, bofs, offs, cursor);
  hipLaunchKernelGGL(edge_pass2, dim3((E + 255) / 256), dim3(256), 0, stream, src, dst, s, t, m, denom, cursor, eidx, E);
  hipLaunchKernelGGL(aggregate_kernel, dim3((N + 3) / 4), dim3(256), 0, stream, offs, eidx, src, s, t, m, denom, z, out, N);
}

// Round 2
// 387.909 us; speedup vs baseline: 1.7530x; 1.7530x over previous
//
#include <hip/hip_runtime.h>
#include <math.h>

#define IN_DIM 128
#define OUT_DIM 64
#define NEG_SLOPE 0.01f

// ---------------- init: count=0 ----------------
__global__ void init_kernel(int* __restrict__ count, int N) {
  int i = blockIdx.x * blockDim.x + threadIdx.x;
  if (i < N) count[i] = 0;
}

// ---------------- fc: z = h @ W ; s = z@a_l ; t = z@a_r ----------------
__global__ __launch_bounds__(256) void fc_kernel(
    const float* __restrict__ h, const float* __restrict__ W,
    const float* __restrict__ al, const float* __restrict__ ar,
    float* __restrict__ z, float* __restrict__ s, float* __restrict__ t, int N) {
  __shared__ float hlds[64][IN_DIM];     // 32 KiB
  __shared__ float Wl[IN_DIM][OUT_DIM];  // 32 KiB
  int tid = threadIdx.x;
  int nb = blockIdx.x * 64;

  for (int i = tid; i < IN_DIM * OUT_DIM / 4; i += 256)
    ((float4*)Wl)[i] = ((const float4*)W)[i];

  for (int it = tid; it < 64 * (IN_DIM / 4); it += 256) {
    int r = it >> 5;
    int kq = it & 31;
    int row = nb + r;
    float4 v = make_float4(0.f, 0.f, 0.f, 0.f);
    if (row < N) v = *(const float4*)&h[(size_t)row * IN_DIM + kq * 4];
    *(float4*)&hlds[r][kq * 4] = v;
  }
  __syncthreads();

  int lane = tid & 63, wid = tid >> 6;
  int n0 = wid * 16;
  float acc[16];
#pragma unroll
  for (int i = 0; i < 16; ++i) acc[i] = 0.f;

  for (int kq = 0; kq < IN_DIM / 4; ++kq) {
    int k = kq * 4;
    float w0 = Wl[k + 0][lane];
    float w1 = Wl[k + 1][lane];
    float w2 = Wl[k + 2][lane];
    float w3 = Wl[k + 3][lane];
#pragma unroll
    for (int nn = 0; nn < 16; ++nn) {
      float4 hv = *(const float4*)&hlds[n0 + nn][k];
      float a = acc[nn];
      a = fmaf(hv.x, w0, a);
      a = fmaf(hv.y, w1, a);
      a = fmaf(hv.z, w2, a);
      a = fmaf(hv.w, w3, a);
      acc[nn] = a;
    }
  }

  float alv = al[lane], arv = ar[lane];
#pragma unroll
  for (int nn = 0; nn < 16; ++nn) {
    int row = nb + n0 + nn;
    float p = acc[nn] * alv;
    float q = acc[nn] * arv;
#pragma unroll
    for (int off = 32; off; off >>= 1) {
      p += __shfl_down(p, off);
      q += __shfl_down(q, off);
    }
    if (row < N) {
      z[(size_t)row * OUT_DIM + lane] = acc[nn];
      if (lane == 0) { s[row] = p; t[row] = q; }
    }
  }
}

// ---------------- edge pass 1: degree count only ----------------
__global__ void edge_pass1(const int* __restrict__ dst, int* __restrict__ count, int E) {
  int i = blockIdx.x * blockDim.x + threadIdx.x;
  if (i < E) atomicAdd(&count[dst[i]], 1);
}

// ---------------- CSR build ----------------
__global__ __launch_bounds__(256) void scan_block_sums(const int* __restrict__ count, int N,
                                                       int* __restrict__ bsums) {
  int b = blockIdx.x, tid = threadIdx.x;
  int base = b * 2048;
  int sum = 0;
  for (int i = tid; i < 2048; i += 256) {
    int idx = base + i;
    if (idx < N) sum += count[idx];
  }
#pragma unroll
  for (int off = 32; off; off >>= 1) sum += __shfl_down(sum, off);
  __shared__ int ws[4];
  int lane = tid & 63, wid = tid >> 6;
  if (lane == 0) ws[wid] = sum;
  __syncthreads();
  if (tid == 0) bsums[b] = ws[0] + ws[1] + ws[2] + ws[3];
}

__global__ void scan_bsums(const int* __restrict__ bsums, int nb, int* __restrict__ bofs,
                           int* __restrict__ offs, int N, int E) {
  if (blockIdx.x == 0 && threadIdx.x == 0) {
    int run = 0;
    for (int i = 0; i < nb; ++i) { bofs[i] = run; run += bsums[i]; }
    offs[N] = E;
  }
}

__global__ __launch_bounds__(256) void scan_write(const int* __restrict__ count, int N,
                                                  const int* __restrict__ bofs,
                                                  int* __restrict__ offs,
                                                  int* __restrict__ cursor) {
  int b = blockIdx.x, tid = threadIdx.x;
  int base = b * 2048 + tid * 8;
  int v[8];
  int tot = 0;
#pragma unroll
  for (int i = 0; i < 8; ++i) {
    int idx = base + i;
    int c = (idx < N) ? count[idx] : 0;
    v[i] = c;
    tot += c;
  }
  int lane = tid & 63, wid = tid >> 6;
  int x = tot;
#pragma unroll
  for (int off = 1; off < 64; off <<= 1) {
    int y = __shfl_up(x, off);
    if (lane >= off) x += y;
  }
  __shared__ int wtot[4];
  if (lane == 63) wtot[wid] = x;
  __syncthreads();
  int wbase = 0;
  for (int w2 = 0; w2 < wid; ++w2) wbase += wtot[w2];
  int run = bofs[b] + wbase + (x - tot);
#pragma unroll
  for (int i = 0; i < 8; ++i) {
    int idx = base + i;
    if (idx < N) { offs[idx] = run; cursor[idx] = run; }
    run += v[i];
  }
}

// ---------------- edge pass 2: scatter {e, src} pairs into CSR order ----------------
__global__ void edge_pass2(const int* __restrict__ src, const int* __restrict__ dst,
                           const float* __restrict__ s, const float* __restrict__ t,
                           int* __restrict__ cursor, float2* __restrict__ pairs, int E) {
  int i = blockIdx.x * blockDim.x + threadIdx.x;
  if (i >= E) return;
  int d = dst[i], sn = src[i];
  float e = s[sn] + t[d];
  e = e > 0.f ? e : NEG_SLOPE * e;
  int pos = atomicAdd(&cursor[d], 1);
  pairs[pos] = make_float2(e, __int_as_float(sn));
}

// ---------------- aggregate: wave per node; pairs in registers; shfl-broadcast ----------------
__global__ __launch_bounds__(256) void aggregate_kernel(
    const int* __restrict__ offs, const float2* __restrict__ pairs,
    const float* __restrict__ z, float* __restrict__ out, int N) {
  int wid = threadIdx.x >> 6, lane = threadIdx.x & 63;
  int n = blockIdx.x * 4 + wid;
  if (n >= N) return;
  int beg = offs[n], end = offs[n + 1];
  int deg = end - beg;
  float acc = 0.f;

  if (deg > 0 && deg <= 64) {
    // lane-parallel pair load (coalesced)
    float e_l = -INFINITY;
    int sn_l = 0;
    if (lane < deg) {
      float2 pr = pairs[beg + lane];
      e_l = pr.x;
      sn_l = __float_as_int(pr.y);
    }
    // wave max
    float mn = e_l;
#pragma unroll
    for (int off = 32; off; off >>= 1) mn = fmaxf(mn, __shfl_xor(mn, off));
    // per-lane weight + wave sum (the softmax denominator)
    float w_l = (lane < deg) ? __expf(e_l - mn) : 0.f;
    float wsum = w_l;
#pragma unroll
    for (int off = 32; off; off >>= 1) wsum += __shfl_xor(wsum, off);
    // broadcast loop over edges, unrolled x4 for independent z-row gathers
    int k = 0;
    for (; k + 4 <= deg; k += 4) {
      int s0 = __shfl(sn_l, k + 0), s1 = __shfl(sn_l, k + 1);
      int s2 = __shfl(sn_l, k + 2), s3 = __shfl(sn_l, k + 3);
      float w0 = __shfl(w_l, k + 0), w1 = __shfl(w_l, k + 1);
      float w2 = __shfl(w_l, k + 2), w3 = __shfl(w_l, k + 3);
      float z0 = z[(size_t)s0 * OUT_DIM + lane];
      float z1 = z[(size_t)s1 * OUT_DIM + lane];
      float z2 = z[(size_t)s2 * OUT_DIM + lane];
      float z3 = z[(size_t)s3 * OUT_DIM + lane];
      acc = fmaf(w0, z0, acc);
      acc = fmaf(w1, z1, acc);
      acc = fmaf(w2, z2, acc);
      acc = fmaf(w3, z3, acc);
    }
    for (; k < deg; ++k) {
      int s0 = __shfl(sn_l, k);
      float w0 = __shfl(w_l, k);
      acc = fmaf(w0, z[(size_t)s0 * OUT_DIM + lane], acc);
    }
    acc /= wsum;
  } else if (deg > 64) {
    // rare fallback: uniform scalar loop
    float mn = -INFINITY;
    for (int p = beg + lane; p < end; p += 64) mn = fmaxf(mn, pairs[p].x);
#pragma unroll
    for (int off = 32; off; off >>= 1) mn = fmaxf(mn, __shfl_xor(mn, off));
    float wsum = 0.f;
    for (int p = beg; p < end; ++p) {
      float2 pr = pairs[p];
      float w = __expf(pr.x - mn);
      wsum += w;
      acc = fmaf(w, z[(size_t)__float_as_int(pr.y) * OUT_DIM + lane], acc);
    }
    acc /= wsum;
  }
  out[(size_t)n * OUT_DIM + lane] = acc;
}

extern "C" void kernel_launch(void* const* d_in, const int* in_sizes, int n_in,
                              void* d_out, int out_size, void* d_ws, size_t ws_size,
                              hipStream_t stream) {
  const float* h = (const float*)d_in[0];
  const int* src = (const int*)d_in[1];
  const int* dst = (const int*)d_in[2];
  const float* W = (const float*)d_in[3];
  const float* al = (const float*)d_in[4];
  const float* ar = (const float*)d_in[5];
  float* out = (float*)d_out;
  int N = in_sizes[0] / IN_DIM;
  int E = in_sizes[1];

  // workspace layout (all written before read every call)
  float* z = (float*)d_ws;                 // N*64
  float* s = z + (size_t)N * OUT_DIM;      // N
  float* t = s + N;                        // N
  int* count = (int*)(t + N);              // N
  int* offs = count + N;                   // N+1
  int* cursor = offs + N + 1;              // N
  float2* pairs = (float2*)(cursor + N);   // E float2
  int* bsums = (int*)(pairs + E);          // <=256
  int* bofs = bsums + 256;                 // <=256

  const int NB = (N + 2047) / 2048;

  hipLaunchKernelGGL(init_kernel, dim3((N + 255) / 256), dim3(256), 0, stream, count, N);
  hipLaunchKernelGGL(fc_kernel, dim3((N + 63) / 64), dim3(256), 0, stream, h, W, al, ar, z, s, t, N);
  hipLaunchKernelGGL(edge_pass1, dim3((E + 255) / 256), dim3(256), 0, stream, dst, count, E);
  hipLaunchKernelGGL(scan_block_sums, dim3(NB), dim3(256), 0, stream, count, N, bsums);
  hipLaunchKernelGGL(scan_bsums, dim3(1), dim3(64), 0, stream, bsums, NB, bofs, offs, N, E);
  hipLaunchKernelGGL(scan_write, dim3(NB), dim3(256), 0, stream, count, N, bofs, offs, cursor);
  hipLaunchKernelGGL(edge_pass2, dim3((E + 255) / 256), dim3(256), 0, stream, src, dst, s, t, cursor, pairs, E);
  hipLaunchKernelGGL(aggregate_kernel, dim3((N + 3) / 4), dim3(256), 0, stream, offs, pairs, z, out, N);
}

// Round 3
// 329.844 us; speedup vs baseline: 2.0616x; 1.1760x over previous
//
#include <hip/hip_runtime.h>
#include <math.h>

#define IN_DIM 128
#define OUT_DIM 64
#define NEG_SLOPE 0.01f

// ---------------- init: count=0 ----------------
__global__ void init_kernel(int* __restrict__ count, int N) {
  int i = blockIdx.x * blockDim.x + threadIdx.x;
  if (i < N) count[i] = 0;
}

// ---------------- fc: z = h @ W ; s = z@a_l ; t = z@a_r ----------------
__global__ __launch_bounds__(256) void fc_kernel(
    const float* __restrict__ h, const float* __restrict__ W,
    const float* __restrict__ al, const float* __restrict__ ar,
    float* __restrict__ z, float* __restrict__ s, float* __restrict__ t, int N) {
  __shared__ float hlds[64][IN_DIM];     // 32 KiB
  __shared__ float Wl[IN_DIM][OUT_DIM];  // 32 KiB
  int tid = threadIdx.x;
  int nb = blockIdx.x * 64;

  for (int i = tid; i < IN_DIM * OUT_DIM / 4; i += 256)
    ((float4*)Wl)[i] = ((const float4*)W)[i];

  for (int it = tid; it < 64 * (IN_DIM / 4); it += 256) {
    int r = it >> 5;
    int kq = it & 31;
    int row = nb + r;
    float4 v = make_float4(0.f, 0.f, 0.f, 0.f);
    if (row < N) v = *(const float4*)&h[(size_t)row * IN_DIM + kq * 4];
    *(float4*)&hlds[r][kq * 4] = v;
  }
  __syncthreads();

  int lane = tid & 63, wid = tid >> 6;
  int n0 = wid * 16;
  float acc[16];
#pragma unroll
  for (int i = 0; i < 16; ++i) acc[i] = 0.f;

  for (int kq = 0; kq < IN_DIM / 4; ++kq) {
    int k = kq * 4;
    float w0 = Wl[k + 0][lane];
    float w1 = Wl[k + 1][lane];
    float w2 = Wl[k + 2][lane];
    float w3 = Wl[k + 3][lane];
#pragma unroll
    for (int nn = 0; nn < 16; ++nn) {
      float4 hv = *(const float4*)&hlds[n0 + nn][k];
      float a = acc[nn];
      a = fmaf(hv.x, w0, a);
      a = fmaf(hv.y, w1, a);
      a = fmaf(hv.z, w2, a);
      a = fmaf(hv.w, w3, a);
      acc[nn] = a;
    }
  }

  float alv = al[lane], arv = ar[lane];
#pragma unroll
  for (int nn = 0; nn < 16; ++nn) {
    int row = nb + n0 + nn;
    float p = acc[nn] * alv;
    float q = acc[nn] * arv;
#pragma unroll
    for (int off = 32; off; off >>= 1) {
      p += __shfl_down(p, off);
      q += __shfl_down(q, off);
    }
    if (row < N) {
      z[(size_t)row * OUT_DIM + lane] = acc[nn];
      if (lane == 0) { s[row] = p; t[row] = q; }
    }
  }
}

// ---------------- edge pass 1: degree count + rank assignment ----------------
__global__ void edge_pass1(const int* __restrict__ dst, int* __restrict__ count,
                           int* __restrict__ rank, int E) {
  int i = blockIdx.x * blockDim.x + threadIdx.x;
  if (i < E) rank[i] = atomicAdd(&count[dst[i]], 1);
}

// ---------------- CSR build ----------------
__global__ __launch_bounds__(256) void scan_block_sums(const int* __restrict__ count, int N,
                                                       int* __restrict__ bsums) {
  int b = blockIdx.x, tid = threadIdx.x;
  int base = b * 2048;
  int sum = 0;
  for (int i = tid; i < 2048; i += 256) {
    int idx = base + i;
    if (idx < N) sum += count[idx];
  }
#pragma unroll
  for (int off = 32; off; off >>= 1) sum += __shfl_down(sum, off);
  __shared__ int ws[4];
  int lane = tid & 63, wid = tid >> 6;
  if (lane == 0) ws[wid] = sum;
  __syncthreads();
  if (tid == 0) bsums[b] = ws[0] + ws[1] + ws[2] + ws[3];
}

__global__ void scan_bsums(const int* __restrict__ bsums, int nb, int* __restrict__ bofs,
                           int* __restrict__ offs, int N, int E) {
  if (blockIdx.x == 0 && threadIdx.x == 0) {
    int run = 0;
    for (int i = 0; i < nb; ++i) { bofs[i] = run; run += bsums[i]; }
    offs[N] = E;
  }
}

__global__ __launch_bounds__(256) void scan_write(const int* __restrict__ count, int N,
                                                  const int* __restrict__ bofs,
                                                  int* __restrict__ offs) {
  int b = blockIdx.x, tid = threadIdx.x;
  int base = b * 2048 + tid * 8;
  int v[8];
  int tot = 0;
#pragma unroll
  for (int i = 0; i < 8; ++i) {
    int idx = base + i;
    int c = (idx < N) ? count[idx] : 0;
    v[i] = c;
    tot += c;
  }
  int lane = tid & 63, wid = tid >> 6;
  int x = tot;
#pragma unroll
  for (int off = 1; off < 64; off <<= 1) {
    int y = __shfl_up(x, off);
    if (lane >= off) x += y;
  }
  __shared__ int wtot[4];
  if (lane == 63) wtot[wid] = x;
  __syncthreads();
  int wbase = 0;
  for (int w2 = 0; w2 < wid; ++w2) wbase += wtot[w2];
  int run = bofs[b] + wbase + (x - tot);
#pragma unroll
  for (int i = 0; i < 8; ++i) {
    int idx = base + i;
    if (idx < N) offs[idx] = run;
    run += v[i];
  }
}

// ---------------- edge pass 2: scatter src into CSR order (no atomics) ----------------
__global__ void edge_pass2(const int* __restrict__ src, const int* __restrict__ dst,
                           const int* __restrict__ rank, const int* __restrict__ offs,
                           int* __restrict__ csr_src, int E) {
  int i = blockIdx.x * blockDim.x + threadIdx.x;
  if (i >= E) return;
  int d = dst[i];
  csr_src[offs[d] + rank[i]] = src[i];
}

// ---------------- aggregate: wave per node ----------------
__global__ __launch_bounds__(256) void aggregate_kernel(
    const int* __restrict__ offs, const int* __restrict__ csr_src,
    const float* __restrict__ s, const float* __restrict__ t,
    const float* __restrict__ z, float* __restrict__ out, int N) {
  int wid = threadIdx.x >> 6, lane = threadIdx.x & 63;
  int n = blockIdx.x * 4 + wid;
  if (n >= N) return;
  int beg = offs[n], end = offs[n + 1];
  int deg = end - beg;
  float acc = 0.f;

  if (deg > 0 && deg <= 64) {
    float tn = t[n];
    // lane-parallel: coalesced src load, then parallel s gather
    float e_l = -INFINITY;
    int sn_l = 0;
    if (lane < deg) {
      sn_l = csr_src[beg + lane];
      float e = s[sn_l] + tn;
      e_l = e > 0.f ? e : NEG_SLOPE * e;
    }
    float mn = e_l;
#pragma unroll
    for (int off = 32; off; off >>= 1) mn = fmaxf(mn, __shfl_xor(mn, off));
    float w_l = (lane < deg) ? __expf(e_l - mn) : 0.f;
    float wsum = w_l;
#pragma unroll
    for (int off = 32; off; off >>= 1) wsum += __shfl_xor(wsum, off);
    // broadcast loop, unrolled x4 for independent z-row gathers
    int k = 0;
    for (; k + 4 <= deg; k += 4) {
      int s0 = __shfl(sn_l, k + 0), s1 = __shfl(sn_l, k + 1);
      int s2 = __shfl(sn_l, k + 2), s3 = __shfl(sn_l, k + 3);
      float w0 = __shfl(w_l, k + 0), w1 = __shfl(w_l, k + 1);
      float w2 = __shfl(w_l, k + 2), w3 = __shfl(w_l, k + 3);
      float z0 = z[(size_t)s0 * OUT_DIM + lane];
      float z1 = z[(size_t)s1 * OUT_DIM + lane];
      float z2 = z[(size_t)s2 * OUT_DIM + lane];
      float z3 = z[(size_t)s3 * OUT_DIM + lane];
      acc = fmaf(w0, z0, acc);
      acc = fmaf(w1, z1, acc);
      acc = fmaf(w2, z2, acc);
      acc = fmaf(w3, z3, acc);
    }
    for (; k < deg; ++k) {
      int s0 = __shfl(sn_l, k);
      float w0 = __shfl(w_l, k);
      acc = fmaf(w0, z[(size_t)s0 * OUT_DIM + lane], acc);
    }
    acc /= wsum;
  } else if (deg > 64) {
    // rare fallback
    float tn = t[n];
    float mn = -INFINITY;
    for (int p = beg + lane; p < end; p += 64) {
      float e = s[csr_src[p]] + tn;
      e = e > 0.f ? e : NEG_SLOPE * e;
      mn = fmaxf(mn, e);
    }
#pragma unroll
    for (int off = 32; off; off >>= 1) mn = fmaxf(mn, __shfl_xor(mn, off));
    float wsum = 0.f;
    for (int p = beg; p < end; ++p) {
      int sn = csr_src[p];
      float e = s[sn] + tn;
      e = e > 0.f ? e : NEG_SLOPE * e;
      float w = __expf(e - mn);
      wsum += w;
      acc = fmaf(w, z[(size_t)sn * OUT_DIM + lane], acc);
    }
    acc /= wsum;
  }
  out[(size_t)n * OUT_DIM + lane] = acc;
}

extern "C" void kernel_launch(void* const* d_in, const int* in_sizes, int n_in,
                              void* d_out, int out_size, void* d_ws, size_t ws_size,
                              hipStream_t stream) {
  const float* h = (const float*)d_in[0];
  const int* src = (const int*)d_in[1];
  const int* dst = (const int*)d_in[2];
  const float* W = (const float*)d_in[3];
  const float* al = (const float*)d_in[4];
  const float* ar = (const float*)d_in[5];
  float* out = (float*)d_out;
  int N = in_sizes[0] / IN_DIM;
  int E = in_sizes[1];

  // workspace layout (all written before read every call)
  float* z = (float*)d_ws;                 // N*64
  float* s = z + (size_t)N * OUT_DIM;      // N
  float* t = s + N;                        // N
  int* count = (int*)(t + N);              // N
  int* offs = count + N;                   // N+1
  int* rank = offs + N + 1;                // E
  int* csr_src = rank + E;                 // E
  int* bsums = csr_src + E;                // <=256
  int* bofs = bsums + 256;                 // <=256

  const int NB = (N + 2047) / 2048;

  hipLaunchKernelGGL(init_kernel, dim3((N + 255) / 256), dim3(256), 0, stream, count, N);
  hipLaunchKernelGGL(fc_kernel, dim3((N + 63) / 64), dim3(256), 0, stream, h, W, al, ar, z, s, t, N);
  hipLaunchKernelGGL(edge_pass1, dim3((E + 255) / 256), dim3(256), 0, stream, dst, count, rank, E);
  hipLaunchKernelGGL(scan_block_sums, dim3(NB), dim3(256), 0, stream, count, N, bsums);
  hipLaunchKernelGGL(scan_bsums, dim3(1), dim3(64), 0, stream, bsums, NB, bofs, offs, N, E);
  hipLaunchKernelGGL(scan_write, dim3(NB), dim3(256), 0, stream, count, N, bofs, offs);
  hipLaunchKernelGGL(edge_pass2, dim3((E + 255) / 256), dim3(256), 0, stream, src, dst, rank, offs, csr_src, E);
  hipLaunchKernelGGL(aggregate_kernel, dim3((N + 3) / 4), dim3(256), 0, stream, offs, csr_src, s, t, z, out, N);
}